// Round 11
// baseline (124.059 us; speedup 1.0000x reference)
//
#include <hip/hip_runtime.h>
#include <math.h>

// Problem constants (B,C,H,W) = (32,1,384,384), fp32 in/out, scalar output.
#define NB   32
#define NH   384
#define NW   384
#define NPIX (NH * NW)
#define KRAD 15
#define KSZ  31
#define INV_DIV (1.0f / 961.0f)
#define EPSV 1e-7f

// ---------------------------------------------------------------------------
// Kernel A: horizontal 31-tap box SUM of target, one block = 4 rows.
// (unchanged — estimated ~5 µs; also zeroes the per-image accumulators.)
// ---------------------------------------------------------------------------
__global__ __launch_bounds__(256) void hbox_kernel(
    const float* __restrict__ tgt,
    float* __restrict__ hsum,
    float* __restrict__ accum)
{
    if (blockIdx.x == 0 && threadIdx.x < 128) accum[threadIdx.x] = 0.0f;

    __shared__ float sp[4][16 + NW + 16];      // left pad 16 => aligned payload

    const int row0 = blockIdx.x * 4;
    const int tid  = threadIdx.x;

    if (tid < 128) {                            // zero the pads
        int r = tid >> 5, j = tid & 31;
        int col = (j < 16) ? j : (16 + NW + (j - 16));
        sp[r][col] = 0.0f;
    }
    for (int i = tid; i < 384; i += 256) {      // stage 4 rows, float4
        int r = i / 96, q = i % 96;
        float4 v = *reinterpret_cast<const float4*>(&tgt[(size_t)(row0 + r) * NW + q * 4]);
        *reinterpret_cast<float4*>(&sp[r][16 + q * 4]) = v;
    }
    __syncthreads();

    const int r  = tid >> 6;
    const int l  = tid & 63;
    const int x0 = l * 6;

    float res[6];
    float w = 0.0f;
    #pragma unroll
    for (int k = 0; k < KSZ; ++k) w += sp[r][x0 + 1 + k];
    res[0] = w;
    #pragma unroll
    for (int i = 1; i < 6; ++i) {
        w += sp[r][x0 + i + 31] - sp[r][x0 + i];
        res[i] = w;
    }
    __syncthreads();

    float* ob = &sp[0][0];                      // reuse as [4][384] for transpose
    #pragma unroll
    for (int i = 0; i < 6; ++i) ob[r * NW + x0 + i] = res[i];
    __syncthreads();
    for (int i = tid; i < 384; i += 256) {
        int rr = i / 96, q = i % 96;
        float4 v = *reinterpret_cast<float4*>(&ob[rr * NW + q * 4]);
        *reinterpret_cast<float4*>(&hsum[(size_t)(row0 + rr) * NW + q * 4]) = v;
    }
}

// ---------------------------------------------------------------------------
// Kernel A2: column-wise inclusive prefix of hsum over y (per image).
// F[y][x] = sum_{r<=y} hsum[r][x]  ->  31-row window = F[y+15] - F[y-16].
// Grid = 32 blocks (1/image), 384 threads (1/column). 16-deep unrolled loads
// keep ~16 independent global reads in flight to hide L2 latency; the add
// chain is serial but trivially cheap.
// ---------------------------------------------------------------------------
__global__ __launch_bounds__(384) void vprefix_kernel(
    const float* __restrict__ hsum,
    float* __restrict__ P)
{
    const int b = blockIdx.x;
    const int x = threadIdx.x;
    const float* __restrict__ src = hsum + (size_t)b * NPIX + x;
    float* __restrict__ dst       = P    + (size_t)b * NPIX + x;

    float run = 0.0f;
    for (int y = 0; y < NH; y += 16) {
        float v[16];
        #pragma unroll
        for (int i = 0; i < 16; ++i) v[i] = src[(size_t)(y + i) * NW];
        #pragma unroll
        for (int i = 0; i < 16; ++i) {
            run += v[i];
            dst[(size_t)(y + i) * NW] = run;
        }
    }
}

// ---------------------------------------------------------------------------
// Elementwise loss math.
// ---------------------------------------------------------------------------
__device__ __forceinline__ void loss_accum(float wsum, float t, float v,
                                           float& s_w, float& s_wb,
                                           float& s_i, float& s_u)
{
    const float bavg = wsum * INV_DIV;
    const float weit = 1.0f + 5.0f * fabsf(bavg - t);
    const float e    = expf(-fabsf(v));           // shared by BCE & sigmoid
    const float wbce = fmaxf(v, 0.0f) - v * t + log1pf(e);
    const float p    = (v >= 0.0f) ? 1.0f / (1.0f + e) : e / (1.0f + e);
    s_w  += weit;
    s_wb += weit * wbce;
    s_i  += p * t * weit;
    s_u  += (p + t) * weit;
}

// ---------------------------------------------------------------------------
// Kernel B (v4): prefix-difference fused loss. NO sliding window, NO serial
// dependency: every row needs only {P[y+15], P[y-16], t, v} — 4 independent
// float4 loads per 4 elements (16 B/elem).
// Block = 384 thr = 96 col-quads x 4 row-groups; thread = 4 cols x 4 rows.
// Grid = 32 imgs x 24 tiles (16 rows) = 768 blocks = 3/CU, 18 waves/CU.
// Tiles 1..22 are branch-free (y>=16 and y+15<=383 guaranteed).
// __launch_bounds__(384,4): VGPR cap 128 — room for many loads in flight.
// ---------------------------------------------------------------------------
__global__ __launch_bounds__(384, 4) void fused_kernel(
    const float* __restrict__ xin,
    const float* __restrict__ tgt,
    const float* __restrict__ P,
    float* __restrict__ accum)
{
    const int blk  = blockIdx.x;
    const int img  = blk / 24;
    const int tile = blk % 24;                 // 16-row tiles
    const int tid  = threadIdx.x;
    const int q    = tid % 96;                 // column quad
    const int rg   = tid / 96;                 // row-group 0..3
    const int c0   = q * 4;
    const int y0   = tile * 16 + rg * 4;       // 4 rows per thread

    const float* __restrict__ Pb = P   + (size_t)img * NPIX;
    const float* __restrict__ tb = tgt + (size_t)img * NPIX;
    const float* __restrict__ ib = xin + (size_t)img * NPIX;

    float s_w = 0.0f, s_wb = 0.0f, s_i = 0.0f, s_u = 0.0f;

    if (tile >= 1 && tile <= 22) {
        // ---- interior fast path: no clamps, lo always present ----
        #pragma unroll
        for (int i = 0; i < 4; ++i) {
            const int y = y0 + i;
            const float4 phi = *reinterpret_cast<const float4*>(&Pb[(size_t)(y + KRAD) * NW + c0]);
            const float4 plo = *reinterpret_cast<const float4*>(&Pb[(size_t)(y - KRAD - 1) * NW + c0]);
            const float4 t4  = *reinterpret_cast<const float4*>(&tb[(size_t)y * NW + c0]);
            const float4 v4  = *reinterpret_cast<const float4*>(&ib[(size_t)y * NW + c0]);
            loss_accum(phi.x - plo.x, t4.x, v4.x, s_w, s_wb, s_i, s_u);
            loss_accum(phi.y - plo.y, t4.y, v4.y, s_w, s_wb, s_i, s_u);
            loss_accum(phi.z - plo.z, t4.z, v4.z, s_w, s_wb, s_i, s_u);
            loss_accum(phi.w - plo.w, t4.w, v4.w, s_w, s_wb, s_i, s_u);
        }
    } else {
        // ---- edge path (tiles 0, 23): clamp hi, drop lo when y<16 ----
        #pragma unroll
        for (int i = 0; i < 4; ++i) {
            const int y   = y0 + i;
            const int yhi = (y + KRAD > NH - 1) ? (NH - 1) : (y + KRAD);
            const float4 phi = *reinterpret_cast<const float4*>(&Pb[(size_t)yhi * NW + c0]);
            float4 plo = make_float4(0.0f, 0.0f, 0.0f, 0.0f);
            if (y >= KRAD + 1)
                plo = *reinterpret_cast<const float4*>(&Pb[(size_t)(y - KRAD - 1) * NW + c0]);
            const float4 t4 = *reinterpret_cast<const float4*>(&tb[(size_t)y * NW + c0]);
            const float4 v4 = *reinterpret_cast<const float4*>(&ib[(size_t)y * NW + c0]);
            loss_accum(phi.x - plo.x, t4.x, v4.x, s_w, s_wb, s_i, s_u);
            loss_accum(phi.y - plo.y, t4.y, v4.y, s_w, s_wb, s_i, s_u);
            loss_accum(phi.z - plo.z, t4.z, v4.z, s_w, s_wb, s_i, s_u);
            loss_accum(phi.w - plo.w, t4.w, v4.w, s_w, s_wb, s_i, s_u);
        }
    }

    // Block reduction: 64-lane shuffle, then LDS across 6 waves.
    #pragma unroll
    for (int off = 32; off > 0; off >>= 1) {
        s_w  += __shfl_down(s_w,  off);
        s_wb += __shfl_down(s_wb, off);
        s_i  += __shfl_down(s_i,  off);
        s_u  += __shfl_down(s_u,  off);
    }
    __shared__ float red[6][4];
    const int lane = tid & 63;
    const int wv   = tid >> 6;
    if (lane == 0) {
        red[wv][0] = s_w; red[wv][1] = s_wb; red[wv][2] = s_i; red[wv][3] = s_u;
    }
    __syncthreads();
    if (tid < 4) {
        float acc = 0.0f;
        #pragma unroll
        for (int i = 0; i < 6; ++i) acc += red[i][tid];
        atomicAdd(&accum[img * 4 + tid], acc);
    }
}

// ---------------------------------------------------------------------------
// Kernel C: per-image wbce/wiou and the mean over 32 images.
// ---------------------------------------------------------------------------
__global__ __launch_bounds__(64) void finalize_kernel(
    const float* __restrict__ accum,
    float* __restrict__ out)
{
    __shared__ float ls[NB];
    const int t = threadIdx.x;
    if (t < NB) {
        const float sw  = accum[4 * t + 0];
        const float swb = accum[4 * t + 1];
        const float si  = accum[4 * t + 2];
        const float su  = accum[4 * t + 3];
        const float wbce = swb / sw;
        const float wiou = 1.0f - (si + 1.0f) / (su - si + 1.0f + EPSV);
        ls[t] = wbce + wiou;
    }
    __syncthreads();
    if (t == 0) {
        float s = 0.0f;
        #pragma unroll
        for (int i = 0; i < NB; ++i) s += ls[i];
        out[0] = s * (1.0f / (float)NB);
    }
}

// ---------------------------------------------------------------------------
extern "C" void kernel_launch(void* const* d_in, const int* in_sizes, int n_in,
                              void* d_out, int out_size, void* d_ws, size_t ws_size,
                              hipStream_t stream)
{
    const float* xin = (const float*)d_in[0];   // "input"  (logits)
    const float* tgt = (const float*)d_in[1];   // "target"
    float* hsum  = (float*)d_ws;                     // NB*NPIX floats (18.9 MB)
    float* P     = hsum + (size_t)NB * NPIX;         // NB*NPIX floats (18.9 MB)
    float* accum = P + (size_t)NB * NPIX;            // 128 floats

    hbox_kernel    <<<(NB * NH) / 4, 256, 0, stream>>>(tgt, hsum, accum);
    vprefix_kernel <<<NB,            384, 0, stream>>>(hsum, P);
    fused_kernel   <<<NB * 24,       384, 0, stream>>>(xin, tgt, P, accum);
    finalize_kernel<<<1,             64,  0, stream>>>(accum, (float*)d_out);
}

// Round 15
// 113.035 us; speedup vs baseline: 1.0975x; 1.0975x over previous
//
#include <hip/hip_runtime.h>
#include <math.h>

// Problem constants (B,C,H,W) = (32,1,384,384), fp32 in/out, scalar output.
#define NB   32
#define NH   384
#define NW   384
#define NPIX (NH * NW)
#define KRAD 15
#define KSZ  31
#define INV_DIV (1.0f / 961.0f)
#define EPSV 1e-7f

// ---------------------------------------------------------------------------
// Kernel A: horizontal 31-tap box SUM of target, one block = 4 rows.
// Also zeroes the per-image accumulators (block 0).
// ---------------------------------------------------------------------------
__global__ __launch_bounds__(256) void hbox_kernel(
    const float* __restrict__ tgt,
    float* __restrict__ hsum,
    float* __restrict__ accum)
{
    if (blockIdx.x == 0 && threadIdx.x < 128) accum[threadIdx.x] = 0.0f;

    __shared__ float sp[4][16 + NW + 16];      // left pad 16 => aligned payload

    const int row0 = blockIdx.x * 4;
    const int tid  = threadIdx.x;

    if (tid < 128) {                            // zero the pads
        int r = tid >> 5, j = tid & 31;
        int col = (j < 16) ? j : (16 + NW + (j - 16));
        sp[r][col] = 0.0f;
    }
    for (int i = tid; i < 384; i += 256) {      // stage 4 rows, float4
        int r = i / 96, q = i % 96;
        float4 v = *reinterpret_cast<const float4*>(&tgt[(size_t)(row0 + r) * NW + q * 4]);
        *reinterpret_cast<float4*>(&sp[r][16 + q * 4]) = v;
    }
    __syncthreads();

    const int r  = tid >> 6;
    const int l  = tid & 63;
    const int x0 = l * 6;

    float res[6];
    float w = 0.0f;
    #pragma unroll
    for (int k = 0; k < KSZ; ++k) w += sp[r][x0 + 1 + k];
    res[0] = w;
    #pragma unroll
    for (int i = 1; i < 6; ++i) {
        w += sp[r][x0 + i + 31] - sp[r][x0 + i];
        res[i] = w;
    }
    __syncthreads();

    float* ob = &sp[0][0];                      // reuse as [4][384] for transpose
    #pragma unroll
    for (int i = 0; i < 6; ++i) ob[r * NW + x0 + i] = res[i];
    __syncthreads();
    for (int i = tid; i < 384; i += 256) {
        int rr = i / 96, q = i % 96;
        float4 v = *reinterpret_cast<float4*>(&ob[rr * NW + q * 4]);
        *reinterpret_cast<float4*>(&hsum[(size_t)(row0 + rr) * NW + q * 4]) = v;
    }
}

// ---------------------------------------------------------------------------
// Elementwise loss math.
// ---------------------------------------------------------------------------
__device__ __forceinline__ void loss_accum(float wsum, float t, float v,
                                           float& s_w, float& s_wb,
                                           float& s_i, float& s_u)
{
    const float bavg = wsum * INV_DIV;
    const float weit = 1.0f + 5.0f * fabsf(bavg - t);
    const float e    = expf(-fabsf(v));           // shared by BCE & sigmoid
    const float wbce = fmaxf(v, 0.0f) - v * t + log1pf(e);
    const float p    = (v >= 0.0f) ? 1.0f / (1.0f + e) : e / (1.0f + e);
    s_w  += weit;
    s_wb += weit * wbce;
    s_i  += p * t * weit;
    s_u  += (p + t) * weit;
}

// ---------------------------------------------------------------------------
// Kernel B (v5): sliding-window fused loss with FULL load hoisting.
// Thread = 1 column x 12 rows. All 67 loads (31 window-init + 12 hadd +
// 12 t + 12 v; hsub rows reuse the init array) are mutually independent and
// issued before any consumption -> ~40-60 outstanding loads/thread to
// saturate L2 BW instead of serializing on latency.
// Grid = 32 imgs x 32 tiles = 1024 blocks; __launch_bounds__(384,4) gives a
// 128-VGPR budget (expected use ~96) -> 16 waves/CU, VGPR-limited.
// ---------------------------------------------------------------------------
__global__ __launch_bounds__(384, 4) void fused_kernel(
    const float* __restrict__ xin,
    const float* __restrict__ tgt,
    const float* __restrict__ hsum,
    float* __restrict__ accum)
{
    const int blk  = blockIdx.x;
    const int img  = ((blk & 7) << 2) | ((blk >> 3) & 3);   // 4 images per XCD
    const int tile = blk >> 5;                              // 0..31
    const int x    = threadIdx.x;                           // column 0..383
    const int y0   = tile * 12;

    const float* __restrict__ hs = hsum + (size_t)img * NPIX + x;
    const float* __restrict__ tb = tgt  + (size_t)img * NPIX + x;
    const float* __restrict__ ib = xin  + (size_t)img * NPIX + x;

    float s_w = 0.0f, s_wb = 0.0f, s_i = 0.0f, s_u = 0.0f;

    const bool interior = (tile >= 2) && (tile <= 29);
    if (interior) {
        // ---- all loads issued up-front, no dependences between them ----
        float iw[KSZ];                      // rows y0-15 .. y0+15
        float ha[12];                       // rows y0+16 .. y0+27
        float tt[12], vv[12];
        #pragma unroll
        for (int k = 0; k < KSZ; ++k) iw[k] = hs[(y0 - KRAD + k) * NW];
        #pragma unroll
        for (int i = 0; i < 12; ++i) ha[i] = hs[(y0 + KRAD + 1 + i) * NW];
        #pragma unroll
        for (int i = 0; i < 12; ++i) tt[i] = tb[(y0 + i) * NW];
        #pragma unroll
        for (int i = 0; i < 12; ++i) vv[i] = ib[(y0 + i) * NW];

        // init window sum: 4 independent partial chains
        float wa = 0.0f, wb = 0.0f, wc = 0.0f, wd = 0.0f;
        #pragma unroll
        for (int k = 0; k < 28; k += 4) {
            wa += iw[k]; wb += iw[k + 1]; wc += iw[k + 2]; wd += iw[k + 3];
        }
        wa += iw[28]; wb += iw[29]; wc += iw[30];
        float w = (wa + wb) + (wc + wd);

        #pragma unroll
        for (int i = 0; i < 12; ++i) {
            loss_accum(w, tt[i], vv[i], s_w, s_wb, s_i, s_u);
            w += ha[i] - iw[i];             // hsub row y0+i-15 == iw[i]
        }
    } else {
        // ---- edge path (tiles 0,1,30,31): predicated window rows ----
        float w = 0.0f;
        #pragma unroll
        for (int k = 0; k < KSZ; ++k) {
            const int rr = y0 - KRAD + k;
            if (rr >= 0 && rr < NH) w += hs[rr * NW];
        }
        #pragma unroll
        for (int yy = 0; yy < 12; ++yy) {
            const int y = y0 + yy;
            const float t = tb[y * NW];
            const float v = ib[y * NW];
            loss_accum(w, t, v, s_w, s_wb, s_i, s_u);
            const int ra = y + KRAD + 1;
            const int rs = y - KRAD;
            if (ra < NH)  w += hs[ra * NW];
            if (rs >= 0)  w -= hs[rs * NW];
        }
    }

    // Block reduction: 64-lane shuffle, then LDS across 6 waves.
    #pragma unroll
    for (int off = 32; off > 0; off >>= 1) {
        s_w  += __shfl_down(s_w,  off);
        s_wb += __shfl_down(s_wb, off);
        s_i  += __shfl_down(s_i,  off);
        s_u  += __shfl_down(s_u,  off);
    }
    __shared__ float red[6][4];
    const int lane = threadIdx.x & 63;
    const int wv   = threadIdx.x >> 6;
    if (lane == 0) {
        red[wv][0] = s_w; red[wv][1] = s_wb; red[wv][2] = s_i; red[wv][3] = s_u;
    }
    __syncthreads();
    if (threadIdx.x < 4) {
        float acc = 0.0f;
        #pragma unroll
        for (int i = 0; i < 6; ++i) acc += red[i][threadIdx.x];
        atomicAdd(&accum[img * 4 + threadIdx.x], acc);
    }
}

// ---------------------------------------------------------------------------
// Kernel C: per-image wbce/wiou and the mean over 32 images.
// ---------------------------------------------------------------------------
__global__ __launch_bounds__(64) void finalize_kernel(
    const float* __restrict__ accum,
    float* __restrict__ out)
{
    __shared__ float ls[NB];
    const int t = threadIdx.x;
    if (t < NB) {
        const float sw  = accum[4 * t + 0];
        const float swb = accum[4 * t + 1];
        const float si  = accum[4 * t + 2];
        const float su  = accum[4 * t + 3];
        const float wbce = swb / sw;
        const float wiou = 1.0f - (si + 1.0f) / (su - si + 1.0f + EPSV);
        ls[t] = wbce + wiou;
    }
    __syncthreads();
    if (t == 0) {
        float s = 0.0f;
        #pragma unroll
        for (int i = 0; i < NB; ++i) s += ls[i];
        out[0] = s * (1.0f / (float)NB);
    }
}

// ---------------------------------------------------------------------------
extern "C" void kernel_launch(void* const* d_in, const int* in_sizes, int n_in,
                              void* d_out, int out_size, void* d_ws, size_t ws_size,
                              hipStream_t stream)
{
    const float* xin = (const float*)d_in[0];   // "input"  (logits)
    const float* tgt = (const float*)d_in[1];   // "target"
    float* hsum  = (float*)d_ws;                // NB*NPIX floats (18.9 MB)
    float* accum = hsum + (size_t)NB * NPIX;    // 128 floats

    hbox_kernel    <<<(NB * NH) / 4, 256, 0, stream>>>(tgt, hsum, accum);
    fused_kernel   <<<NB * 32,       384, 0, stream>>>(xin, tgt, hsum, accum);
    finalize_kernel<<<1,             64,  0, stream>>>(accum, (float*)d_out);
}

// Round 17
// 101.209 us; speedup vs baseline: 1.2258x; 1.1168x over previous
//
#include <hip/hip_runtime.h>
#include <math.h>

// Problem constants (B,C,H,W) = (32,1,384,384), fp32 in/out, scalar output.
#define NB   32
#define NH   384
#define NW   384
#define NPIX (NH * NW)
#define KRAD 15
#define KSZ  31
#define INV_DIV (1.0f / 961.0f)
#define EPSV 1e-7f

// ---------------------------------------------------------------------------
// Kernel A: horizontal 31-tap box SUM of target, one block = 4 rows.
// Also zeroes the per-image accumulators (block 0).
// ---------------------------------------------------------------------------
__global__ __launch_bounds__(256) void hbox_kernel(
    const float* __restrict__ tgt,
    float* __restrict__ hsum,
    float* __restrict__ accum)
{
    if (blockIdx.x == 0 && threadIdx.x < 128) accum[threadIdx.x] = 0.0f;

    __shared__ float sp[4][16 + NW + 16];      // left pad 16 => aligned payload

    const int row0 = blockIdx.x * 4;
    const int tid  = threadIdx.x;

    if (tid < 128) {                            // zero the pads
        int r = tid >> 5, j = tid & 31;
        int col = (j < 16) ? j : (16 + NW + (j - 16));
        sp[r][col] = 0.0f;
    }
    for (int i = tid; i < 384; i += 256) {      // stage 4 rows, float4
        int r = i / 96, q = i % 96;
        float4 v = *reinterpret_cast<const float4*>(&tgt[(size_t)(row0 + r) * NW + q * 4]);
        *reinterpret_cast<float4*>(&sp[r][16 + q * 4]) = v;
    }
    __syncthreads();

    const int r  = tid >> 6;
    const int l  = tid & 63;
    const int x0 = l * 6;

    float res[6];
    float w = 0.0f;
    #pragma unroll
    for (int k = 0; k < KSZ; ++k) w += sp[r][x0 + 1 + k];
    res[0] = w;
    #pragma unroll
    for (int i = 1; i < 6; ++i) {
        w += sp[r][x0 + i + 31] - sp[r][x0 + i];
        res[i] = w;
    }
    __syncthreads();

    float* ob = &sp[0][0];                      // reuse as [4][384] for transpose
    #pragma unroll
    for (int i = 0; i < 6; ++i) ob[r * NW + x0 + i] = res[i];
    __syncthreads();
    for (int i = tid; i < 384; i += 256) {
        int rr = i / 96, q = i % 96;
        float4 v = *reinterpret_cast<float4*>(&ob[rr * NW + q * 4]);
        *reinterpret_cast<float4*>(&hsum[(size_t)(row0 + rr) * NW + q * 4]) = v;
    }
}

// ---------------------------------------------------------------------------
// Elementwise loss math — fast-transcendental version.
// __expf/__logf map to v_exp_f32/v_log_f32 (quarter-rate HW ops);
// rcp replaces the precise-division sequence. Errors ~1e-6 vs libm
// (measured absmax was 0.0 with libm — ample headroom).
// log1p(e) == log(1+e) is well-conditioned here since e in (0,1].
// ---------------------------------------------------------------------------
__device__ __forceinline__ void loss_accum(float wsum, float t, float v,
                                           float& s_w, float& s_wb,
                                           float& s_i, float& s_u)
{
    const float bavg = wsum * INV_DIV;
    const float weit = 1.0f + 5.0f * fabsf(bavg - t);
    const float e    = __expf(-fabsf(v));             // shared by BCE & sigmoid
    const float opeI = __builtin_amdgcn_rcpf(1.0f + e); // 1/(1+e)
    const float wbce = fmaxf(v, 0.0f) - v * t + __logf(1.0f + e);
    const float p    = (v >= 0.0f) ? opeI : e * opeI; // sigmoid, both branches cheap
    s_w  += weit;
    s_wb += weit * wbce;
    s_i  += p * t * weit;
    s_u  += (p + t) * weit;
}

// ---------------------------------------------------------------------------
// Kernel B (v6): sliding-window fused loss, load hoist PINNED via asm.
// v5's flaw (measured r15): compiler reported VGPR_Count=40 — it sank the
// 67 hoisted loads back to their uses, destroying memory-level parallelism.
// The memory-clobber asm below forbids sinking loads past it, forcing all
// 67 values live simultaneously (~70-110 VGPR) and all loads issued in one
// burst -> the 12 HBM-miss xin loads (~900cy, L3 thrashed by the 268MB
// ws-fill) and 55 L2 loads overlap in a single latency window.
// Grid = 32 imgs x 32 tiles = 1024 blocks; __launch_bounds__(384,4) = 128
// VGPR budget, 4 blocks/CU, 24 waves/CU.
// ---------------------------------------------------------------------------
__global__ __launch_bounds__(384, 4) void fused_kernel(
    const float* __restrict__ xin,
    const float* __restrict__ tgt,
    const float* __restrict__ hsum,
    float* __restrict__ accum)
{
    const int blk  = blockIdx.x;
    const int img  = ((blk & 7) << 2) | ((blk >> 3) & 3);   // 4 images per XCD
    const int tile = blk >> 5;                              // 0..31
    const int x    = threadIdx.x;                           // column 0..383
    const int y0   = tile * 12;

    const float* __restrict__ hs = hsum + (size_t)img * NPIX + x;
    const float* __restrict__ tb = tgt  + (size_t)img * NPIX + x;
    const float* __restrict__ ib = xin  + (size_t)img * NPIX + x;

    float s_w = 0.0f, s_wb = 0.0f, s_i = 0.0f, s_u = 0.0f;

    const bool interior = (tile >= 2) && (tile <= 29);
    if (interior) {
        // ---- issue ALL loads up-front; nothing may sink below the pin ----
        float iw[KSZ];                      // hsum rows y0-15 .. y0+15
        float ha[12];                       // hsum rows y0+16 .. y0+27
        float tt[12], vv[12];
        #pragma unroll
        for (int k = 0; k < KSZ; ++k) iw[k] = hs[(y0 - KRAD + k) * NW];
        #pragma unroll
        for (int i = 0; i < 12; ++i) ha[i] = hs[(y0 + KRAD + 1 + i) * NW];
        #pragma unroll
        for (int i = 0; i < 12; ++i) tt[i] = tb[(y0 + i) * NW];
        #pragma unroll
        for (int i = 0; i < 12; ++i) vv[i] = ib[(y0 + i) * NW];
        asm volatile("" ::: "memory");      // PIN: loads may not sink past here

        // init window sum: 4 independent partial chains
        float wa = 0.0f, wb = 0.0f, wc = 0.0f, wd = 0.0f;
        #pragma unroll
        for (int k = 0; k < 28; k += 4) {
            wa += iw[k]; wb += iw[k + 1]; wc += iw[k + 2]; wd += iw[k + 3];
        }
        wa += iw[28]; wb += iw[29]; wc += iw[30];
        float w = (wa + wb) + (wc + wd);

        #pragma unroll
        for (int i = 0; i < 12; ++i) {
            loss_accum(w, tt[i], vv[i], s_w, s_wb, s_i, s_u);
            w += ha[i] - iw[i];             // hsub row y0+i-15 == iw[i]
        }
    } else {
        // ---- edge path (tiles 0,1,30,31): predicated window rows ----
        float w = 0.0f;
        #pragma unroll
        for (int k = 0; k < KSZ; ++k) {
            const int rr = y0 - KRAD + k;
            if (rr >= 0 && rr < NH) w += hs[rr * NW];
        }
        #pragma unroll
        for (int yy = 0; yy < 12; ++yy) {
            const int y = y0 + yy;
            const float t = tb[y * NW];
            const float v = ib[y * NW];
            loss_accum(w, t, v, s_w, s_wb, s_i, s_u);
            const int ra = y + KRAD + 1;
            const int rs = y - KRAD;
            if (ra < NH)  w += hs[ra * NW];
            if (rs >= 0)  w -= hs[rs * NW];
        }
    }

    // Block reduction: 64-lane shuffle, then LDS across 6 waves.
    #pragma unroll
    for (int off = 32; off > 0; off >>= 1) {
        s_w  += __shfl_down(s_w,  off);
        s_wb += __shfl_down(s_wb, off);
        s_i  += __shfl_down(s_i,  off);
        s_u  += __shfl_down(s_u,  off);
    }
    __shared__ float red[6][4];
    const int lane = threadIdx.x & 63;
    const int wv   = threadIdx.x >> 6;
    if (lane == 0) {
        red[wv][0] = s_w; red[wv][1] = s_wb; red[wv][2] = s_i; red[wv][3] = s_u;
    }
    __syncthreads();
    if (threadIdx.x < 4) {
        float acc = 0.0f;
        #pragma unroll
        for (int i = 0; i < 6; ++i) acc += red[i][threadIdx.x];
        atomicAdd(&accum[img * 4 + threadIdx.x], acc);
    }
}

// ---------------------------------------------------------------------------
// Kernel C: per-image wbce/wiou and the mean over 32 images.
// ---------------------------------------------------------------------------
__global__ __launch_bounds__(64) void finalize_kernel(
    const float* __restrict__ accum,
    float* __restrict__ out)
{
    __shared__ float ls[NB];
    const int t = threadIdx.x;
    if (t < NB) {
        const float sw  = accum[4 * t + 0];
        const float swb = accum[4 * t + 1];
        const float si  = accum[4 * t + 2];
        const float su  = accum[4 * t + 3];
        const float wbce = swb / sw;
        const float wiou = 1.0f - (si + 1.0f) / (su - si + 1.0f + EPSV);
        ls[t] = wbce + wiou;
    }
    __syncthreads();
    if (t == 0) {
        float s = 0.0f;
        #pragma unroll
        for (int i = 0; i < NB; ++i) s += ls[i];
        out[0] = s * (1.0f / (float)NB);
    }
}

// ---------------------------------------------------------------------------
extern "C" void kernel_launch(void* const* d_in, const int* in_sizes, int n_in,
                              void* d_out, int out_size, void* d_ws, size_t ws_size,
                              hipStream_t stream)
{
    const float* xin = (const float*)d_in[0];   // "input"  (logits)
    const float* tgt = (const float*)d_in[1];   // "target"
    float* hsum  = (float*)d_ws;                // NB*NPIX floats (18.9 MB)
    float* accum = hsum + (size_t)NB * NPIX;    // 128 floats

    hbox_kernel    <<<(NB * NH) / 4, 256, 0, stream>>>(tgt, hsum, accum);
    fused_kernel   <<<NB * 32,       384, 0, stream>>>(xin, tgt, hsum, accum);
    finalize_kernel<<<1,             64,  0, stream>>>(accum, (float*)d_out);
}